// Round 1
// baseline (26001.263 us; speedup 1.0000x reference)
//
#include <hip/hip_runtime.h>
#include <hip/hip_bf16.h>
#include <cstdint>
#include <cstddef>

typedef short bf16x8 __attribute__((ext_vector_type(8)));
typedef float f32x4  __attribute__((ext_vector_type(4)));
typedef __hip_bfloat16 bf16;

#define NT_T 512
#define NB   64
#define NI   512
#define NH   1024
#define NO   512

// ---------------- workspace layout (bytes, all 256-aligned) ----------------
static constexpr size_t OFF_XBF   = 0;                                  // x as bf16 [512*64*512]
static constexpr size_t SZ_XBF    = (size_t)NT_T * NB * NI * 2;         // 33,554,432
static constexpr size_t OFF_WSW0  = OFF_XBF + SZ_XBF;                   // layer0 frag-swizzled W (128 blocks x 96KB)
static constexpr size_t SZ_WSW0   = 128ull * 98304;
static constexpr size_t OFF_WSW1  = OFF_WSW0 + SZ_WSW0;                 // layer1 frag-swizzled W (128 blocks x 128KB)
static constexpr size_t SZ_WSW1   = 128ull * 131072;
static constexpr size_t OFF_WOUT  = OFF_WSW1 + SZ_WSW1;                 // W_out bf16 [512*1024]
static constexpr size_t SZ_WOUT   = (size_t)NO * NH * 2;
static constexpr size_t OFF_B0    = OFF_WOUT + SZ_WOUT;                 // bias0 = b_ih0+b_hh0 (fp32, 4096)
static constexpr size_t OFF_B1    = OFF_B0 + 4096 * 4;                  // bias1
static constexpr size_t OFF_H1    = OFF_B1 + 4096 * 4;                  // h1 ping-pong [2][64][1024] bf16
static constexpr size_t OFF_H2    = OFF_H1 + 2ull * NB * NH * 2;        // h2 history [512][64][1024] bf16
static constexpr size_t OFF_FLAGS = OFF_H2 + (size_t)NT_T * NB * NH * 2;// 256 ints (barrier flags)
// total ~131.4 MB

__device__ __forceinline__ float sigm(float x) {
  return 1.0f / (1.0f + __expf(-x));
}
__device__ __forceinline__ float tanh_fast(float x) {
  x = fminf(15.0f, fmaxf(-15.0f, x));
  const float e = __expf(2.0f * x);
  return (e - 1.0f) / (e + 1.0f);
}

// ---------------- prep kernels ----------------
__global__ void k_convert_x(const float* __restrict__ x, bf16* __restrict__ xbf) {
  const size_t n = (size_t)NT_T * NB * NI;
  for (size_t i = (size_t)blockIdx.x * blockDim.x + threadIdx.x; i < n;
       i += (size_t)gridDim.x * blockDim.x)
    xbf[i] = __float2bfloat16(x[i]);
}

// Build per-block, per-lane fragment-ordered weight images for the recurrence.
// B-fragment of mfma_f32_16x16x32_bf16: lane l holds B[n = l&15][k = (l>>4)*8 + j], j=0..7.
// Layout: [blk][nt(2)][ks][lane(64)][j(8)] with K-concat: L0 = [W_ih0 | W_hh0] (K=1536, ks 0..47),
// L1 = [W_ih1 | W_hh1] (K=2048, ks 0..63). Gate rows within a block: [i(8) f(8) g(8) o(8)] for cols blk*8..+8.
__global__ void k_build_wsw(const float* __restrict__ Wih0, const float* __restrict__ Whh0,
                            const float* __restrict__ Wih1, const float* __restrict__ Whh1,
                            bf16* __restrict__ wsw0, bf16* __restrict__ wsw1) {
  const size_t L0N = 128ull * 2 * 48 * 64 * 8;  // 6,291,456
  const size_t L1N = 128ull * 2 * 64 * 64 * 8;  // 8,388,608
  const size_t n = L0N + L1N;
  for (size_t i = (size_t)blockIdx.x * blockDim.x + threadIdx.x; i < n;
       i += (size_t)gridDim.x * blockDim.x) {
    if (i < L0N) {
      size_t idx = i;
      const int j = idx & 7;    idx >>= 3;
      const int lane = idx & 63; idx >>= 6;
      const int ks = (int)(idx % 48); idx /= 48;
      const int nt = idx & 1;
      const int blk = (int)(idx >> 1);
      const int nl = nt * 16 + (lane & 15);
      const int k = ks * 32 + (lane >> 4) * 8 + j;
      const int grow = (nl >> 3) * 1024 + blk * 8 + (nl & 7);
      const float v = (k < 512) ? Wih0[(size_t)grow * 512 + k]
                                : Whh0[(size_t)grow * 1024 + (k - 512)];
      wsw0[i] = __float2bfloat16(v);
    } else {
      size_t idx = i - L0N;
      const size_t o = idx;
      const int j = idx & 7;    idx >>= 3;
      const int lane = idx & 63; idx >>= 6;
      const int ks = (int)(idx % 64); idx /= 64;
      const int nt = idx & 1;
      const int blk = (int)(idx >> 1);
      const int nl = nt * 16 + (lane & 15);
      const int k = ks * 32 + (lane >> 4) * 8 + j;
      const int grow = (nl >> 3) * 1024 + blk * 8 + (nl & 7);
      const float v = (k < 1024) ? Wih1[(size_t)grow * 1024 + k]
                                 : Whh1[(size_t)grow * 1024 + (k - 1024)];
      wsw1[o] = __float2bfloat16(v);
    }
  }
}

__global__ void k_small(const float* __restrict__ Wout,
                        const float* __restrict__ bih0, const float* __restrict__ bhh0,
                        const float* __restrict__ bih1, const float* __restrict__ bhh1,
                        bf16* __restrict__ woutbf, float* __restrict__ bias0,
                        float* __restrict__ bias1, int* __restrict__ flags) {
  const int i = blockIdx.x * 256 + threadIdx.x;
  if (i < NO * NH) woutbf[i] = __float2bfloat16(Wout[i]);
  if (i < 4096) {
    bias0[i] = bih0[i] + bhh0[i];
    bias1[i] = bih1[i] + bhh1[i];
  }
  if (i < 256) flags[i] = 0;
}

// ---------------- persistent fused 2-layer LSTM recurrence ----------------
// grid = 256 blocks x 256 threads, 1 block/CU (136KB LDS). blocks 0..127: layer0, 128..255: layer1.
// Block owns 8 h-columns (32 gate rows). Layer1 runs one timestep behind layer0 (pipelined).
// Waves: (mh = batch-half of 32, kh = K-half). K fuses input GEMM: L0 [x|h1prev] K=1536, L1 [h1|h2prev] K=2048.
__global__ __launch_bounds__(256) void lstm_recur(
    const bf16* __restrict__ xbf, const bf16* __restrict__ wsw0, const bf16* __restrict__ wsw1,
    const float* __restrict__ bias0, const float* __restrict__ bias1,
    bf16* __restrict__ h1buf, bf16* __restrict__ h2hist, int* __restrict__ flags) {
  __shared__ char Wlds[131072];       // frag-swizzled weight slice (L0 uses 96KB, L1 128KB)
  __shared__ float red[64][32];       // kh-reduction + gate exchange

  const int tid = threadIdx.x;
  const int bid = blockIdx.x;
  const int layer = bid >> 7;
  const int blk = bid & 127;
  const int lane = tid & 63;
  const int wid = tid >> 6;
  const int mh = wid & 1;
  const int kh = wid >> 1;
  const int q = lane >> 4;
  const int ml = lane & 15;
  const int colbase = blk * 8;

  { // load weight slice into LDS once; barrier-fence-proof for all 513 steps
    const char* src = layer ? (const char*)wsw1 + (size_t)blk * 131072
                            : (const char*)wsw0 + (size_t)blk * 98304;
    const int nb = layer ? 131072 : 98304;
    for (int off = tid * 16; off < nb; off += 256 * 16)
      *(uint4*)(Wlds + off) = *(const uint4*)(src + off);
  }

  float biasv[2];
  {
    const float* bs = layer ? bias1 : bias0;
#pragma unroll
    for (int nt = 0; nt < 2; ++nt) {
      const int nl = nt * 16 + ml;
      biasv[nt] = bs[(nl >> 3) * 1024 + colbase + (nl & 7)];
    }
  }
  __syncthreads();

  const int KS  = layer ? 64 : 48;   // total 32-wide k-steps
  const int KSh = layer ? 32 : 24;   // per kh-wave

  float cstate[2] = {0.f, 0.f};      // fp32 cell state in registers
  const bf16x8 zv = {};
  const f32x4 zacc = {0.f, 0.f, 0.f, 0.f};

  for (int it = 0; it <= NT_T; ++it) {
    const int t = layer ? (it - 1) : it;
    const bool active = (t >= 0) && (t < NT_T);
    if (active) {
      const bf16* h1prev = h1buf + (size_t)((t - 1) & 1) * (NB * NH);
      const bf16* h1cur  = h1buf + (size_t)(t & 1) * (NB * NH);

      f32x4 acc[2][2];
#pragma unroll
      for (int a1 = 0; a1 < 2; ++a1)
#pragma unroll
        for (int a2 = 0; a2 < 2; ++a2) acc[a1][a2] = zacc;

      for (int ksl = 0; ksl < KSh; ++ksl) {
        const int ksg = kh * KSh + ksl;
        const int kg = ksg * 32;
        const int klane = kg + q * 8;
        bf16x8 a[2];
#pragma unroll
        for (int mt = 0; mt < 2; ++mt) {
          const int m = mh * 32 + mt * 16 + ml;
          const bf16* src = nullptr;
          if (layer == 0) {
            if (kg < 512)      src = xbf + ((size_t)t * NB + m) * NI + klane;
            else if (t > 0)    src = h1prev + (size_t)m * NH + (klane - 512);
          } else {
            if (kg < 1024)     src = h1cur + (size_t)m * NH + klane;
            else if (t > 0)    src = h2hist + ((size_t)(t - 1) * NB + m) * NH + (klane - 1024);
          }
          a[mt] = src ? *(const bf16x8*)src : zv;
        }
#pragma unroll
        for (int nt = 0; nt < 2; ++nt) {
          const bf16x8 b = *(const bf16x8*)(Wlds + ((size_t)(nt * KS + ksg) * 64 + lane) * 16);
          acc[0][nt] = __builtin_amdgcn_mfma_f32_16x16x32_bf16(a[0], b, acc[0][nt], 0, 0, 0);
          acc[1][nt] = __builtin_amdgcn_mfma_f32_16x16x32_bf16(a[1], b, acc[1][nt], 0, 0, 0);
        }
      }

      // cross-kh reduction: kh==1 publishes partials, kh==0 combines + bias, writes full gates
      if (kh == 1) {
#pragma unroll
        for (int mt = 0; mt < 2; ++mt)
#pragma unroll
          for (int nt = 0; nt < 2; ++nt)
#pragma unroll
            for (int r = 0; r < 4; ++r)
              red[mh * 32 + mt * 16 + q * 4 + r][nt * 16 + ml] = acc[mt][nt][r];
      }
      __syncthreads();
      if (kh == 0) {
#pragma unroll
        for (int mt = 0; mt < 2; ++mt)
#pragma unroll
          for (int nt = 0; nt < 2; ++nt)
#pragma unroll
            for (int r = 0; r < 4; ++r) {
              const int mloc = mh * 32 + mt * 16 + q * 4 + r;
              const int nloc = nt * 16 + ml;
              red[mloc][nloc] = acc[mt][nt][r] + red[mloc][nloc] + biasv[nt];
            }
      }
      __syncthreads();

      // elementwise LSTM cell: 512 (batch, col) items, 2 per thread
#pragma unroll
      for (int e = 0; e < 2; ++e) {
        const int item = e * 256 + tid;
        const int b = item >> 3;
        const int cc = item & 7;
        const float gi = red[b][cc];
        const float gf = red[b][8 + cc];
        const float gg = red[b][16 + cc];
        const float go = red[b][24 + cc];
        const float cn = sigm(gf) * cstate[e] + sigm(gi) * tanh_fast(gg);
        cstate[e] = cn;
        const float hv = sigm(go) * tanh_fast(cn);
        const bf16 hb = __float2bfloat16(hv);
        if (layer == 0)
          h1buf[(size_t)(t & 1) * (NB * NH) + (size_t)b * NH + colbase + cc] = hb;
        else
          h2hist[((size_t)t * NB + b) * NH + colbase + cc] = hb;
      }
    }

    // ---- device-wide barrier (all 256 blocks co-resident: grid == #CUs, 1 block/CU) ----
    __syncthreads();  // drains this block's global stores (waitcnt before s_barrier)
    if (tid == 0)
      __hip_atomic_store(&flags[bid], it + 1, __ATOMIC_RELEASE, __HIP_MEMORY_SCOPE_AGENT);
    if (tid < 64) {
      const int tgt = it + 1;
      for (;;) {
        const int v0 = __hip_atomic_load(&flags[tid],       __ATOMIC_RELAXED, __HIP_MEMORY_SCOPE_AGENT);
        const int v1 = __hip_atomic_load(&flags[tid + 64],  __ATOMIC_RELAXED, __HIP_MEMORY_SCOPE_AGENT);
        const int v2 = __hip_atomic_load(&flags[tid + 128], __ATOMIC_RELAXED, __HIP_MEMORY_SCOPE_AGENT);
        const int v3 = __hip_atomic_load(&flags[tid + 192], __ATOMIC_RELAXED, __HIP_MEMORY_SCOPE_AGENT);
        const int ok = (v0 >= tgt) && (v1 >= tgt) && (v2 >= tgt) && (v3 >= tgt);
        if (__all(ok)) break;
        __builtin_amdgcn_s_sleep(2);
      }
    }
    __syncthreads();
    __threadfence();  // acquire: invalidate stale L2 so h written on other XCDs is visible
  }
}

// ---------------- output projection: [32768,1024] @ [512,1024]^T + b_out ----------------
__global__ __launch_bounds__(256) void gemm_out(
    const bf16* __restrict__ A, const bf16* __restrict__ B,
    const float* __restrict__ bout, float* __restrict__ out) {
  __shared__ char As[8192];
  __shared__ char Bs[8192];
  const int tid = threadIdx.x;
  const int lane = tid & 63;
  const int wid = tid >> 6;
  const int wm = wid >> 1;
  const int wn = wid & 1;
  const size_t Mbase = (size_t)blockIdx.y * 128;
  const int Nbase = blockIdx.x * 128;

  const f32x4 zacc = {0.f, 0.f, 0.f, 0.f};
  f32x4 acc[4][4];
#pragma unroll
  for (int i = 0; i < 4; ++i)
#pragma unroll
    for (int j = 0; j < 4; ++j) acc[i][j] = zacc;

  for (int kc = 0; kc < 32; ++kc) {
    const int kb = kc * 32;
#pragma unroll
    for (int e = 0; e < 2; ++e) {
      const int id = e * 256 + tid;
      const int r = id >> 2;
      const int c8 = (id & 3) * 8;
      const int dst = ((r >> 4) * 64 + (c8 >> 3) * 16 + (r & 15)) * 16;
      *(uint4*)(As + dst) = *(const uint4*)(A + (Mbase + r) * NH + kb + c8);
      *(uint4*)(Bs + dst) = *(const uint4*)(B + (size_t)(Nbase + r) * NH + kb + c8);
    }
    __syncthreads();
    bf16x8 af[4], bfr[4];
#pragma unroll
    for (int i = 0; i < 4; ++i) {
      af[i]  = *(const bf16x8*)(As + ((wm * 4 + i) * 64 + lane) * 16);
      bfr[i] = *(const bf16x8*)(Bs + ((wn * 4 + i) * 64 + lane) * 16);
    }
#pragma unroll
    for (int i = 0; i < 4; ++i)
#pragma unroll
      for (int j = 0; j < 4; ++j)
        acc[i][j] = __builtin_amdgcn_mfma_f32_16x16x32_bf16(af[i], bfr[j], acc[i][j], 0, 0, 0);
    __syncthreads();
  }
  const int qq = lane >> 4, ml = lane & 15;
#pragma unroll
  for (int i = 0; i < 4; ++i)
#pragma unroll
    for (int j = 0; j < 4; ++j)
#pragma unroll
      for (int r = 0; r < 4; ++r) {
        const size_t m = Mbase + wm * 64 + i * 16 + qq * 4 + r;
        const int n = Nbase + wn * 64 + j * 16 + ml;
        out[m * NO + n] = acc[i][j][r] + bout[n];
      }
}

// ---------------- host ----------------
extern "C" void kernel_launch(void* const* d_in, const int* in_sizes, int n_in,
                              void* d_out, int out_size, void* d_ws, size_t ws_size,
                              hipStream_t stream) {
  (void)in_sizes; (void)n_in; (void)out_size; (void)ws_size;
  const float* x    = (const float*)d_in[0];
  const float* Wih0 = (const float*)d_in[1];
  const float* Whh0 = (const float*)d_in[2];
  const float* bih0 = (const float*)d_in[3];
  const float* bhh0 = (const float*)d_in[4];
  const float* Wih1 = (const float*)d_in[5];
  const float* Whh1 = (const float*)d_in[6];
  const float* bih1 = (const float*)d_in[7];
  const float* bhh1 = (const float*)d_in[8];
  const float* Wout = (const float*)d_in[9];
  const float* bout = (const float*)d_in[10];
  float* out = (float*)d_out;
  char* ws = (char*)d_ws;

  bf16*  xbf    = (bf16*)(ws + OFF_XBF);
  bf16*  wsw0   = (bf16*)(ws + OFF_WSW0);
  bf16*  wsw1   = (bf16*)(ws + OFF_WSW1);
  bf16*  woutbf = (bf16*)(ws + OFF_WOUT);
  float* bias0  = (float*)(ws + OFF_B0);
  float* bias1  = (float*)(ws + OFF_B1);
  bf16*  h1buf  = (bf16*)(ws + OFF_H1);
  bf16*  h2hist = (bf16*)(ws + OFF_H2);
  int*   flags  = (int*)(ws + OFF_FLAGS);

  k_convert_x<<<8192, 256, 0, stream>>>(x, xbf);
  k_build_wsw<<<14336, 256, 0, stream>>>(Wih0, Whh0, Wih1, Whh1, wsw0, wsw1);
  k_small<<<2048, 256, 0, stream>>>(Wout, bih0, bhh0, bih1, bhh1, woutbf, bias0, bias1, flags);
  lstm_recur<<<256, 256, 0, stream>>>(xbf, wsw0, wsw1, bias0, bias1, h1buf, h2hist, flags);
  gemm_out<<<dim3(4, 256), 256, 0, stream>>>(h2hist, woutbf, bout, out);
}

// Round 2
// 11085.484 us; speedup vs baseline: 2.3455x; 2.3455x over previous
//
#include <hip/hip_runtime.h>
#include <hip/hip_bf16.h>
#include <cstdint>
#include <cstddef>

typedef short bf16x8 __attribute__((ext_vector_type(8)));
typedef float f32x4  __attribute__((ext_vector_type(4)));
typedef __hip_bfloat16 bf16;
typedef unsigned long long u64;

#define NT_T 512
#define NB   64
#define NI   512
#define NH   1024
#define NO   512

// ---------------- workspace layout (bytes, all 256-aligned) ----------------
static constexpr size_t OFF_XBF   = 0;                                  // x as bf16 [512*64*512]
static constexpr size_t SZ_XBF    = (size_t)NT_T * NB * NI * 2;         // 33,554,432
static constexpr size_t OFF_WSW0  = OFF_XBF + SZ_XBF;                   // layer0 frag-swizzled W (128 blocks x 96KB)
static constexpr size_t SZ_WSW0   = 128ull * 98304;
static constexpr size_t OFF_WSW1  = OFF_WSW0 + SZ_WSW0;                 // layer1 frag-swizzled W (128 blocks x 128KB)
static constexpr size_t SZ_WSW1   = 128ull * 131072;
static constexpr size_t OFF_WOUT  = OFF_WSW1 + SZ_WSW1;                 // W_out bf16 [512*1024]
static constexpr size_t SZ_WOUT   = (size_t)NO * NH * 2;
static constexpr size_t OFF_B0    = OFF_WOUT + SZ_WOUT;                 // bias0 = b_ih0+b_hh0 (fp32, 4096)
static constexpr size_t OFF_B1    = OFF_B0 + 4096 * 4;                  // bias1
static constexpr size_t OFF_H1    = OFF_B1 + 4096 * 4;                  // h1 ping-pong [2][64][1024] bf16
static constexpr size_t OFF_H2    = OFF_H1 + 2ull * NB * NH * 2;        // h2 history [512][64][1024] bf16
static constexpr size_t OFF_FLAGS = OFF_H2 + (size_t)NT_T * NB * NH * 2;// 256 ints (barrier flags)

__device__ __forceinline__ float sigm(float x) {
  return 1.0f / (1.0f + __expf(-x));
}
__device__ __forceinline__ float tanh_fast(float x) {
  x = fminf(15.0f, fmaxf(-15.0f, x));
  const float e = __expf(2.0f * x);
  return (e - 1.0f) / (e + 1.0f);
}

// coherent (sc1, L2-bypassing) 16B h-fragment load as 2x b64 relaxed agent atomics
__device__ __forceinline__ bf16x8 load_h8(const bf16* p) {
  union { u64 q[2]; bf16x8 v; } u;
  const u64* pp = (const u64*)p;
  u.q[0] = __hip_atomic_load(pp,     __ATOMIC_RELAXED, __HIP_MEMORY_SCOPE_AGENT);
  u.q[1] = __hip_atomic_load(pp + 1, __ATOMIC_RELAXED, __HIP_MEMORY_SCOPE_AGENT);
  return u.v;
}

// ---------------- prep kernels ----------------
__global__ void k_convert_x(const float* __restrict__ x, bf16* __restrict__ xbf) {
  const size_t n = (size_t)NT_T * NB * NI;
  for (size_t i = (size_t)blockIdx.x * blockDim.x + threadIdx.x; i < n;
       i += (size_t)gridDim.x * blockDim.x)
    xbf[i] = __float2bfloat16(x[i]);
}

// Build per-block, per-lane fragment-ordered weight images for the recurrence.
// B-fragment of mfma_f32_16x16x32_bf16: lane l holds B[n = l&15][k = (l>>4)*8 + j], j=0..7.
// Layout: [blk][nt(2)][ks][lane(64)][j(8)]; K-concat: L0 = [W_ih0 | W_hh0] (K=1536, ks 0..47),
// L1 = [W_ih1 | W_hh1] (K=2048, ks 0..63). Gate rows per block: [i(8) f(8) g(8) o(8)] for cols blk*8..+8.
__global__ void k_build_wsw(const float* __restrict__ Wih0, const float* __restrict__ Whh0,
                            const float* __restrict__ Wih1, const float* __restrict__ Whh1,
                            bf16* __restrict__ wsw0, bf16* __restrict__ wsw1) {
  const size_t L0N = 128ull * 2 * 48 * 64 * 8;
  const size_t L1N = 128ull * 2 * 64 * 64 * 8;
  const size_t n = L0N + L1N;
  for (size_t i = (size_t)blockIdx.x * blockDim.x + threadIdx.x; i < n;
       i += (size_t)gridDim.x * blockDim.x) {
    if (i < L0N) {
      size_t idx = i;
      const int j = idx & 7;    idx >>= 3;
      const int lane = idx & 63; idx >>= 6;
      const int ks = (int)(idx % 48); idx /= 48;
      const int nt = idx & 1;
      const int blk = (int)(idx >> 1);
      const int nl = nt * 16 + (lane & 15);
      const int k = ks * 32 + (lane >> 4) * 8 + j;
      const int grow = (nl >> 3) * 1024 + blk * 8 + (nl & 7);
      const float v = (k < 512) ? Wih0[(size_t)grow * 512 + k]
                                : Whh0[(size_t)grow * 1024 + (k - 512)];
      wsw0[i] = __float2bfloat16(v);
    } else {
      size_t idx = i - L0N;
      const size_t o = idx;
      const int j = idx & 7;    idx >>= 3;
      const int lane = idx & 63; idx >>= 6;
      const int ks = (int)(idx % 64); idx /= 64;
      const int nt = idx & 1;
      const int blk = (int)(idx >> 1);
      const int nl = nt * 16 + (lane & 15);
      const int k = ks * 32 + (lane >> 4) * 8 + j;
      const int grow = (nl >> 3) * 1024 + blk * 8 + (nl & 7);
      const float v = (k < 1024) ? Wih1[(size_t)grow * 1024 + k]
                                 : Whh1[(size_t)grow * 1024 + (k - 1024)];
      wsw1[o] = __float2bfloat16(v);
    }
  }
}

__global__ void k_small(const float* __restrict__ Wout,
                        const float* __restrict__ bih0, const float* __restrict__ bhh0,
                        const float* __restrict__ bih1, const float* __restrict__ bhh1,
                        bf16* __restrict__ woutbf, float* __restrict__ bias0,
                        float* __restrict__ bias1, int* __restrict__ flags) {
  const int i = blockIdx.x * 256 + threadIdx.x;
  if (i < NO * NH) woutbf[i] = __float2bfloat16(Wout[i]);
  if (i < 4096) {
    bias0[i] = bih0[i] + bhh0[i];
    bias1[i] = bih1[i] + bhh1[i];
  }
  if (i < 256) flags[i] = 0;
}

// ---------------- persistent fused 2-layer LSTM recurrence ----------------
// grid = 256 blocks x 256 threads, 1 block/CU (139.5KB LDS). blocks 0..127: layer0, 128..255: layer1.
// Cross-block h/flag traffic is ALL relaxed agent-scope atomics (sc1: bypass L2, coherent at
// Infinity Cache) -> no release/acquire fences, no buffer_wbl2 / buffer_inv per iteration.
__global__ __launch_bounds__(256) void lstm_recur(
    const bf16* __restrict__ xbf, const bf16* __restrict__ wsw0, const bf16* __restrict__ wsw1,
    const float* __restrict__ bias0, const float* __restrict__ bias1,
    bf16* __restrict__ h1buf, bf16* __restrict__ h2hist, int* __restrict__ flags) {
  __shared__ char Wlds[131072];       // frag-swizzled weight slice (L0 96KB, L1 128KB)
  __shared__ float red[64][33];       // kh-reduction + gate exchange (padded: no bank conflicts)

  const int tid = threadIdx.x;
  const int bid = blockIdx.x;
  const int layer = bid >> 7;
  const int blk = bid & 127;
  const int lane = tid & 63;
  const int wid = tid >> 6;
  const int mh = wid & 1;
  const int kh = wid >> 1;
  const int q = lane >> 4;
  const int ml = lane & 15;
  const int colbase = blk * 8;

  { // weight slice -> LDS once; immune to everything (no cache ops in the loop anyway now)
    const char* src = layer ? (const char*)wsw1 + (size_t)blk * 131072
                            : (const char*)wsw0 + (size_t)blk * 98304;
    const int nb = layer ? 131072 : 98304;
    for (int off = tid * 16; off < nb; off += 256 * 16)
      *(uint4*)(Wlds + off) = *(const uint4*)(src + off);
  }

  float biasv[2];
  {
    const float* bs = layer ? bias1 : bias0;
#pragma unroll
    for (int nt = 0; nt < 2; ++nt) {
      const int nl = nt * 16 + ml;
      biasv[nt] = bs[(nl >> 3) * 1024 + colbase + (nl & 7)];
    }
  }
  __syncthreads();

  const int KS  = layer ? 64 : 48;   // total 32-wide k-steps
  const int KSh = layer ? 32 : 24;   // per kh-wave

  float cstate[2] = {0.f, 0.f};      // fp32 cell state in registers (thread owns rows b=tid>>2, cols cc0..cc0+1)
  const f32x4 zacc = {0.f, 0.f, 0.f, 0.f};

  for (int it = 0; it <= NT_T; ++it) {
    const int t = layer ? (it - 1) : it;
    const bool active = (t >= 0) && (t < NT_T);
    if (active) {
      const bf16* h1prev = h1buf + (size_t)((t - 1) & 1) * (NB * NH);
      const bf16* h1cur  = h1buf + (size_t)(t & 1) * (NB * NH);
      const bf16* h2prev = h2hist + (size_t)(t - 1) * (NB * NH);

      f32x4 acc[2][2];
#pragma unroll
      for (int a1 = 0; a1 < 2; ++a1)
#pragma unroll
        for (int a2 = 0; a2 < 2; ++a2) acc[a1][a2] = zacc;

      // generic K-region: ks in [s,e), A rows from src (row stride rs), k offset koff
      auto mm = [&](const bf16* src, int rs, int s, int e, int koff, bool coh) {
#pragma unroll 4
        for (int ks = s; ks < e; ++ks) {
          const int kl = ks * 32 + q * 8 - koff;
          bf16x8 a[2];
#pragma unroll
          for (int mt = 0; mt < 2; ++mt) {
            const bf16* p = src + (size_t)(mh * 32 + mt * 16 + ml) * rs + kl;
            a[mt] = coh ? load_h8(p) : *(const bf16x8*)p;
          }
#pragma unroll
          for (int nt = 0; nt < 2; ++nt) {
            const bf16x8 b = *(const bf16x8*)(Wlds + ((size_t)(nt * KS + ks) * 64 + lane) * 16);
            acc[0][nt] = __builtin_amdgcn_mfma_f32_16x16x32_bf16(a[0], b, acc[0][nt], 0, 0, 0);
            acc[1][nt] = __builtin_amdgcn_mfma_f32_16x16x32_bf16(a[1], b, acc[1][nt], 0, 0, 0);
          }
        }
      };

      const int s = kh * KSh, e = s + KSh;
      if (layer == 0) {
        const int xe = e < 16 ? e : 16;
        if (s < 16)            mm(xbf + (size_t)t * NB * NI, NI, s, xe, 0, false);
        const int hs = s > 16 ? s : 16;
        if (t > 0 && hs < e)   mm(h1prev, NH, hs, e, 512, true);
      } else {
        if (s < 32)            mm(h1cur, NH, s, e, 0, true);       // kh==0: [0,32)
        else if (t > 0)        mm(h2prev, NH, s, e, 1024, true);   // kh==1: [32,64)
      }

      // cross-kh reduction: kh==1 publishes partials, kh==0 combines + bias
      if (kh == 1) {
#pragma unroll
        for (int mt = 0; mt < 2; ++mt)
#pragma unroll
          for (int nt = 0; nt < 2; ++nt)
#pragma unroll
            for (int r = 0; r < 4; ++r)
              red[mh * 32 + mt * 16 + q * 4 + r][nt * 16 + ml] = acc[mt][nt][r];
      }
      __syncthreads();
      if (kh == 0) {
#pragma unroll
        for (int mt = 0; mt < 2; ++mt)
#pragma unroll
          for (int nt = 0; nt < 2; ++nt)
#pragma unroll
            for (int r = 0; r < 4; ++r) {
              const int mloc = mh * 32 + mt * 16 + q * 4 + r;
              const int nloc = nt * 16 + ml;
              red[mloc][nloc] = acc[mt][nt][r] + red[mloc][nloc] + biasv[nt];
            }
      }
      __syncthreads();

      // elementwise LSTM cell: thread owns (b = tid>>2, cc0 = (tid&3)*2, cc0+1) -> one packed 4B store
      {
        const int b = tid >> 2;
        const int cc0 = (tid & 3) * 2;
        unsigned short hb[2];
#pragma unroll
        for (int e2 = 0; e2 < 2; ++e2) {
          const int cc = cc0 + e2;
          const float gi = red[b][cc];
          const float gf = red[b][8 + cc];
          const float gg = red[b][16 + cc];
          const float go = red[b][24 + cc];
          const float cn = sigm(gf) * cstate[e2] + sigm(gi) * tanh_fast(gg);
          cstate[e2] = cn;
          const float hv = sigm(go) * tanh_fast(cn);
          hb[e2] = __builtin_bit_cast(unsigned short, __float2bfloat16(hv));
        }
        const unsigned int packed = (unsigned int)hb[0] | ((unsigned int)hb[1] << 16);
        bf16* dstbase = layer ? (h2hist + ((size_t)t * NB + b) * NH)
                              : (h1buf + (size_t)(t & 1) * (NB * NH) + (size_t)b * NH);
        __hip_atomic_store((unsigned int*)(dstbase + colbase + cc0), packed,
                           __ATOMIC_RELAXED, __HIP_MEMORY_SCOPE_AGENT);
      }
    }

    // ---- fence-free device barrier (256 blocks co-resident; flags via sc1 atomics) ----
    __syncthreads();  // vmcnt(0): sc1 h-stores acked at coherence point before flag store
    if (tid == 0)
      __hip_atomic_store(&flags[bid], it + 1, __ATOMIC_RELAXED, __HIP_MEMORY_SCOPE_AGENT);
    if (tid < 64) {
      const int tgt = it + 1;
      for (;;) {
        const int v0 = __hip_atomic_load(&flags[tid],       __ATOMIC_RELAXED, __HIP_MEMORY_SCOPE_AGENT);
        const int v1 = __hip_atomic_load(&flags[tid + 64],  __ATOMIC_RELAXED, __HIP_MEMORY_SCOPE_AGENT);
        const int v2 = __hip_atomic_load(&flags[tid + 128], __ATOMIC_RELAXED, __HIP_MEMORY_SCOPE_AGENT);
        const int v3 = __hip_atomic_load(&flags[tid + 192], __ATOMIC_RELAXED, __HIP_MEMORY_SCOPE_AGENT);
        const int ok = (v0 >= tgt) && (v1 >= tgt) && (v2 >= tgt) && (v3 >= tgt);
        if (__all(ok)) break;
        __builtin_amdgcn_s_sleep(1);
      }
    }
    __syncthreads();
    // no __threadfence(): readers use sc1 loads (L2-bypassing), writers used sc1 stores
  }
}

// ---------------- output projection: [32768,1024] @ [512,1024]^T + b_out ----------------
__global__ __launch_bounds__(256) void gemm_out(
    const bf16* __restrict__ A, const bf16* __restrict__ B,
    const float* __restrict__ bout, float* __restrict__ out) {
  __shared__ char As[8192];
  __shared__ char Bs[8192];
  const int tid = threadIdx.x;
  const int lane = tid & 63;
  const int wid = tid >> 6;
  const int wm = wid >> 1;
  const int wn = wid & 1;
  const size_t Mbase = (size_t)blockIdx.y * 128;
  const int Nbase = blockIdx.x * 128;

  const f32x4 zacc = {0.f, 0.f, 0.f, 0.f};
  f32x4 acc[4][4];
#pragma unroll
  for (int i = 0; i < 4; ++i)
#pragma unroll
    for (int j = 0; j < 4; ++j) acc[i][j] = zacc;

  for (int kc = 0; kc < 32; ++kc) {
    const int kb = kc * 32;
#pragma unroll
    for (int e = 0; e < 2; ++e) {
      const int id = e * 256 + tid;
      const int r = id >> 2;
      const int c8 = (id & 3) * 8;
      const int dst = ((r >> 4) * 64 + (c8 >> 3) * 16 + (r & 15)) * 16;
      *(uint4*)(As + dst) = *(const uint4*)(A + (Mbase + r) * NH + kb + c8);
      *(uint4*)(Bs + dst) = *(const uint4*)(B + (size_t)(Nbase + r) * NH + kb + c8);
    }
    __syncthreads();
    bf16x8 af[4], bfr[4];
#pragma unroll
    for (int i = 0; i < 4; ++i) {
      af[i]  = *(const bf16x8*)(As + ((wm * 4 + i) * 64 + lane) * 16);
      bfr[i] = *(const bf16x8*)(Bs + ((wn * 4 + i) * 64 + lane) * 16);
    }
#pragma unroll
    for (int i = 0; i < 4; ++i)
#pragma unroll
      for (int j = 0; j < 4; ++j)
        acc[i][j] = __builtin_amdgcn_mfma_f32_16x16x32_bf16(af[i], bfr[j], acc[i][j], 0, 0, 0);
    __syncthreads();
  }
  const int qq = lane >> 4, ml = lane & 15;
#pragma unroll
  for (int i = 0; i < 4; ++i)
#pragma unroll
    for (int j = 0; j < 4; ++j)
#pragma unroll
      for (int r = 0; r < 4; ++r) {
        const size_t m = Mbase + wm * 64 + i * 16 + qq * 4 + r;
        const int n = Nbase + wn * 64 + j * 16 + ml;
        out[m * NO + n] = acc[i][j][r] + bout[n];
      }
}

// ---------------- host ----------------
extern "C" void kernel_launch(void* const* d_in, const int* in_sizes, int n_in,
                              void* d_out, int out_size, void* d_ws, size_t ws_size,
                              hipStream_t stream) {
  (void)in_sizes; (void)n_in; (void)out_size; (void)ws_size;
  const float* x    = (const float*)d_in[0];
  const float* Wih0 = (const float*)d_in[1];
  const float* Whh0 = (const float*)d_in[2];
  const float* bih0 = (const float*)d_in[3];
  const float* bhh0 = (const float*)d_in[4];
  const float* Wih1 = (const float*)d_in[5];
  const float* Whh1 = (const float*)d_in[6];
  const float* bih1 = (const float*)d_in[7];
  const float* bhh1 = (const float*)d_in[8];
  const float* Wout = (const float*)d_in[9];
  const float* bout = (const float*)d_in[10];
  float* out = (float*)d_out;
  char* ws = (char*)d_ws;

  bf16*  xbf    = (bf16*)(ws + OFF_XBF);
  bf16*  wsw0   = (bf16*)(ws + OFF_WSW0);
  bf16*  wsw1   = (bf16*)(ws + OFF_WSW1);
  bf16*  woutbf = (bf16*)(ws + OFF_WOUT);
  float* bias0  = (float*)(ws + OFF_B0);
  float* bias1  = (float*)(ws + OFF_B1);
  bf16*  h1buf  = (bf16*)(ws + OFF_H1);
  bf16*  h2hist = (bf16*)(ws + OFF_H2);
  int*   flags  = (int*)(ws + OFF_FLAGS);

  k_convert_x<<<8192, 256, 0, stream>>>(x, xbf);
  k_build_wsw<<<14336, 256, 0, stream>>>(Wih0, Whh0, Wih1, Whh1, wsw0, wsw1);
  k_small<<<2048, 256, 0, stream>>>(Wout, bih0, bhh0, bih1, bhh1, woutbf, bias0, bias1, flags);
  lstm_recur<<<256, 256, 0, stream>>>(xbf, wsw0, wsw1, bias0, bias1, h1buf, h2hist, flags);
  gemm_out<<<dim3(4, 256), 256, 0, stream>>>(h2hist, woutbf, bout, out);
}

// Round 3
// 8666.245 us; speedup vs baseline: 3.0003x; 1.2792x over previous
//
#include <hip/hip_runtime.h>
#include <hip/hip_bf16.h>
#include <cstdint>
#include <cstddef>

typedef short bf16x8 __attribute__((ext_vector_type(8)));
typedef float f32x4  __attribute__((ext_vector_type(4)));
typedef __hip_bfloat16 bf16;
typedef unsigned long long u64;

#define NT_T 512
#define NB   64
#define NI   512
#define NH   1024
#define NO   512

// h history slots: 64x1024 bf16 + 128-element pad so no cache line straddles slots
// (write-once addresses => plain cached loads are coherent; pad defeats any
// adjacent-line pull-in across the slot boundary)
static constexpr size_t SLOT_E = (size_t)NB * NH + 128;   // elements (bf16)
static constexpr size_t SLOT_B = SLOT_E * 2;              // 131,328 bytes (256-aligned)

// ---------------- workspace layout (bytes, all 256-aligned) ----------------
static constexpr size_t OFF_XBF   = 0;                                  // x as bf16 [512*64*512]
static constexpr size_t SZ_XBF    = (size_t)NT_T * NB * NI * 2;         // 33,554,432
static constexpr size_t OFF_WSW0  = OFF_XBF + SZ_XBF;                   // layer0 frag-swizzled W
static constexpr size_t SZ_WSW0   = 128ull * 98304;
static constexpr size_t OFF_WSW1  = OFF_WSW0 + SZ_WSW0;                 // layer1 frag-swizzled W
static constexpr size_t SZ_WSW1   = 128ull * 131072;
static constexpr size_t OFF_WOUT  = OFF_WSW1 + SZ_WSW1;                 // W_out bf16 [512*1024]
static constexpr size_t SZ_WOUT   = (size_t)NO * NH * 2;
static constexpr size_t OFF_B0    = OFF_WOUT + SZ_WOUT;                 // bias0 = b_ih0+b_hh0 (fp32)
static constexpr size_t OFF_B1    = OFF_B0 + 4096 * 4;                  // bias1
static constexpr size_t OFF_H1    = OFF_B1 + 4096 * 4;                  // h1 history [512 slots]
static constexpr size_t SZ_H1     = (size_t)NT_T * SLOT_B;              // 67,239,936
static constexpr size_t OFF_H2    = OFF_H1 + SZ_H1;                     // h2 history [512 slots]
static constexpr size_t SZ_H2     = (size_t)NT_T * SLOT_B;
static constexpr size_t OFF_FLAGS = OFF_H2 + SZ_H2;                     // 256 ints (barrier flags)
// total ~198.5 MB

__device__ __forceinline__ float sigm(float x) {
  return 1.0f / (1.0f + __expf(-x));
}
__device__ __forceinline__ float tanh_fast(float x) {
  x = fminf(15.0f, fmaxf(-15.0f, x));
  const float e = __expf(2.0f * x);
  return (e - 1.0f) / (e + 1.0f);
}

// ---------------- prep kernels ----------------
__global__ void k_convert_x(const float* __restrict__ x, bf16* __restrict__ xbf) {
  const size_t n = (size_t)NT_T * NB * NI;
  for (size_t i = (size_t)blockIdx.x * blockDim.x + threadIdx.x; i < n;
       i += (size_t)gridDim.x * blockDim.x)
    xbf[i] = __float2bfloat16(x[i]);
}

// Build per-block, per-lane fragment-ordered weight images for the recurrence.
// B-fragment of mfma_f32_16x16x32_bf16: lane l holds B[n = l&15][k = (l>>4)*8 + j], j=0..7.
// Layout: [blk][nt(2)][ks][lane(64)][j(8)]; K-concat: L0 = [W_ih0 | W_hh0] (K=1536, ks 0..47),
// L1 = [W_ih1 | W_hh1] (K=2048, ks 0..63). Gate rows per block: [i(8) f(8) g(8) o(8)] for cols blk*8..+8.
__global__ void k_build_wsw(const float* __restrict__ Wih0, const float* __restrict__ Whh0,
                            const float* __restrict__ Wih1, const float* __restrict__ Whh1,
                            bf16* __restrict__ wsw0, bf16* __restrict__ wsw1) {
  const size_t L0N = 128ull * 2 * 48 * 64 * 8;
  const size_t L1N = 128ull * 2 * 64 * 64 * 8;
  const size_t n = L0N + L1N;
  for (size_t i = (size_t)blockIdx.x * blockDim.x + threadIdx.x; i < n;
       i += (size_t)gridDim.x * blockDim.x) {
    if (i < L0N) {
      size_t idx = i;
      const int j = idx & 7;    idx >>= 3;
      const int lane = idx & 63; idx >>= 6;
      const int ks = (int)(idx % 48); idx /= 48;
      const int nt = idx & 1;
      const int blk = (int)(idx >> 1);
      const int nl = nt * 16 + (lane & 15);
      const int k = ks * 32 + (lane >> 4) * 8 + j;
      const int grow = (nl >> 3) * 1024 + blk * 8 + (nl & 7);
      const float v = (k < 512) ? Wih0[(size_t)grow * 512 + k]
                                : Whh0[(size_t)grow * 1024 + (k - 512)];
      wsw0[i] = __float2bfloat16(v);
    } else {
      size_t idx = i - L0N;
      const size_t o = idx;
      const int j = idx & 7;    idx >>= 3;
      const int lane = idx & 63; idx >>= 6;
      const int ks = (int)(idx % 64); idx /= 64;
      const int nt = idx & 1;
      const int blk = (int)(idx >> 1);
      const int nl = nt * 16 + (lane & 15);
      const int k = ks * 32 + (lane >> 4) * 8 + j;
      const int grow = (nl >> 3) * 1024 + blk * 8 + (nl & 7);
      const float v = (k < 1024) ? Wih1[(size_t)grow * 1024 + k]
                                 : Whh1[(size_t)grow * 1024 + (k - 1024)];
      wsw1[o] = __float2bfloat16(v);
    }
  }
}

__global__ void k_small(const float* __restrict__ Wout,
                        const float* __restrict__ bih0, const float* __restrict__ bhh0,
                        const float* __restrict__ bih1, const float* __restrict__ bhh1,
                        bf16* __restrict__ woutbf, float* __restrict__ bias0,
                        float* __restrict__ bias1, int* __restrict__ flags) {
  const int i = blockIdx.x * 256 + threadIdx.x;
  if (i < NO * NH) woutbf[i] = __float2bfloat16(Wout[i]);
  if (i < 4096) {
    bias0[i] = bih0[i] + bhh0[i];
    bias1[i] = bih1[i] + bhh1[i];
  }
  if (i < 256) flags[i] = 0;
}

// ---------------- persistent fused 2-layer LSTM recurrence ----------------
// grid = 256 blocks x 256 threads, 1 block/CU. blocks 0..127: layer0, 128..255: layer1.
// h buffers are WRITE-ONCE slot histories -> consumers use plain pipelined b128 loads
// (coherent by construction: first touch is a compulsory miss served from the IC).
// Producers store via relaxed agent-scope (sc1 write-through) atomics; barrier flags
// are sc1 atomics both ways.
__global__ __launch_bounds__(256) void lstm_recur(
    const bf16* __restrict__ xbf, const bf16* __restrict__ wsw0, const bf16* __restrict__ wsw1,
    const float* __restrict__ bias0, const float* __restrict__ bias1,
    bf16* __restrict__ h1hist, bf16* __restrict__ h2hist, int* __restrict__ flags) {
  __shared__ char Wlds[131072];       // frag-swizzled weight slice (L0 96KB, L1 128KB)
  __shared__ float red[64][33];       // kh-reduction + gate exchange

  const int tid = threadIdx.x;
  const int bid = blockIdx.x;
  const int layer = bid >> 7;
  const int blk = bid & 127;
  const int lane = tid & 63;
  const int wid = tid >> 6;
  const int mh = wid & 1;
  const int kh = wid >> 1;
  const int q = lane >> 4;
  const int ml = lane & 15;
  const int colbase = blk * 8;

  { // weight slice -> LDS once
    const char* src = layer ? (const char*)wsw1 + (size_t)blk * 131072
                            : (const char*)wsw0 + (size_t)blk * 98304;
    const int nb = layer ? 131072 : 98304;
    for (int off = tid * 16; off < nb; off += 256 * 16)
      *(uint4*)(Wlds + off) = *(const uint4*)(src + off);
  }

  float biasv[2];
  {
    const float* bs = layer ? bias1 : bias0;
#pragma unroll
    for (int nt = 0; nt < 2; ++nt) {
      const int nl = nt * 16 + ml;
      biasv[nt] = bs[(nl >> 3) * 1024 + colbase + (nl & 7)];
    }
  }
  __syncthreads();

  const int KS  = layer ? 64 : 48;   // total 32-wide k-steps
  const int KSh = layer ? 32 : 24;   // per kh-wave

  float cstate[2] = {0.f, 0.f};
  const f32x4 zacc = {0.f, 0.f, 0.f, 0.f};

  for (int it = 0; it <= NT_T; ++it) {
    const int t = layer ? (it - 1) : it;
    const bool active = (t >= 0) && (t < NT_T);
    if (active) {
      const bf16* h1prev = h1hist + (size_t)(t - 1) * SLOT_E;  // valid iff t>0
      const bf16* h1cur  = h1hist + (size_t)t * SLOT_E;
      const bf16* h2prev = h2hist + (size_t)(t - 1) * SLOT_E;  // valid iff t>0

      f32x4 acc[2][2];
#pragma unroll
      for (int a1 = 0; a1 < 2; ++a1)
#pragma unroll
        for (int a2 = 0; a2 < 2; ++a2) acc[a1][a2] = zacc;

      // K-region: ks in [s,e), A rows from src (row stride rs), k offset koff.
      // Plain b128 loads; unroll 8 -> deep vmcnt pipeline (no atomics on this path).
      auto mm = [&](const bf16* src, int rs, int s, int e, int koff) {
#pragma unroll 8
        for (int ks = s; ks < e; ++ks) {
          const int kl = ks * 32 + q * 8 - koff;
          bf16x8 a[2];
#pragma unroll
          for (int mt = 0; mt < 2; ++mt)
            a[mt] = *(const bf16x8*)(src + (size_t)(mh * 32 + mt * 16 + ml) * rs + kl);
#pragma unroll
          for (int nt = 0; nt < 2; ++nt) {
            const bf16x8 b = *(const bf16x8*)(Wlds + ((size_t)(nt * KS + ks) * 64 + lane) * 16);
            acc[0][nt] = __builtin_amdgcn_mfma_f32_16x16x32_bf16(a[0], b, acc[0][nt], 0, 0, 0);
            acc[1][nt] = __builtin_amdgcn_mfma_f32_16x16x32_bf16(a[1], b, acc[1][nt], 0, 0, 0);
          }
        }
      };

      const int s = kh * KSh, e = s + KSh;
      if (layer == 0) {
        const int xe = e < 16 ? e : 16;
        if (s < 16)            mm(xbf + (size_t)t * NB * NI, NI, s, xe, 0);
        const int hs = s > 16 ? s : 16;
        if (t > 0 && hs < e)   mm(h1prev, NH, hs, e, 512);
      } else {
        if (s < 32)            mm(h1cur, NH, s, e, 0);        // kh==0: [0,32)
        else if (t > 0)        mm(h2prev, NH, s, e, 1024);    // kh==1: [32,64)
      }

      // cross-kh reduction: kh==1 publishes partials, kh==0 combines + bias
      if (kh == 1) {
#pragma unroll
        for (int mt = 0; mt < 2; ++mt)
#pragma unroll
          for (int nt = 0; nt < 2; ++nt)
#pragma unroll
            for (int r = 0; r < 4; ++r)
              red[mh * 32 + mt * 16 + q * 4 + r][nt * 16 + ml] = acc[mt][nt][r];
      }
      __syncthreads();
      if (kh == 0) {
#pragma unroll
        for (int mt = 0; mt < 2; ++mt)
#pragma unroll
          for (int nt = 0; nt < 2; ++nt)
#pragma unroll
            for (int r = 0; r < 4; ++r) {
              const int mloc = mh * 32 + mt * 16 + q * 4 + r;
              const int nloc = nt * 16 + ml;
              red[mloc][nloc] = acc[mt][nt][r] + red[mloc][nloc] + biasv[nt];
            }
      }
      __syncthreads();

      // elementwise LSTM cell: thread owns (b = tid>>2, cc0 = (tid&3)*2, +1) -> one packed 4B store
      {
        const int b = tid >> 2;
        const int cc0 = (tid & 3) * 2;
        unsigned short hb[2];
#pragma unroll
        for (int e2 = 0; e2 < 2; ++e2) {
          const int cc = cc0 + e2;
          const float gi = red[b][cc];
          const float gf = red[b][8 + cc];
          const float gg = red[b][16 + cc];
          const float go = red[b][24 + cc];
          const float cn = sigm(gf) * cstate[e2] + sigm(gi) * tanh_fast(gg);
          cstate[e2] = cn;
          const float hv = sigm(go) * tanh_fast(cn);
          hb[e2] = __builtin_bit_cast(unsigned short, __float2bfloat16(hv));
        }
        const unsigned int packed = (unsigned int)hb[0] | ((unsigned int)hb[1] << 16);
        bf16* dstbase = (layer ? h2hist : h1hist) + (size_t)t * SLOT_E + (size_t)b * NH;
        __hip_atomic_store((unsigned int*)(dstbase + colbase + cc0), packed,
                           __ATOMIC_RELAXED, __HIP_MEMORY_SCOPE_AGENT);
      }
    }

    // ---- fence-free device barrier (256 blocks co-resident; flags via sc1 atomics) ----
    __syncthreads();  // vmcnt(0): sc1 h-stores acked at coherence point before flag store
    if (tid == 0)
      __hip_atomic_store(&flags[bid], it + 1, __ATOMIC_RELAXED, __HIP_MEMORY_SCOPE_AGENT);
    if (tid < 64) {
      const int tgt = it + 1;
      for (;;) {
        const int v0 = __hip_atomic_load(&flags[tid],       __ATOMIC_RELAXED, __HIP_MEMORY_SCOPE_AGENT);
        const int v1 = __hip_atomic_load(&flags[tid + 64],  __ATOMIC_RELAXED, __HIP_MEMORY_SCOPE_AGENT);
        const int v2 = __hip_atomic_load(&flags[tid + 128], __ATOMIC_RELAXED, __HIP_MEMORY_SCOPE_AGENT);
        const int v3 = __hip_atomic_load(&flags[tid + 192], __ATOMIC_RELAXED, __HIP_MEMORY_SCOPE_AGENT);
        const int ok = (v0 >= tgt) && (v1 >= tgt) && (v2 >= tgt) && (v3 >= tgt);
        if (__all(ok)) break;
        __builtin_amdgcn_s_sleep(1);
      }
    }
    __syncthreads();
  }
}

// ---------------- output projection: h2hist(slots) @ W_out^T + b_out ----------------
__global__ __launch_bounds__(256) void gemm_out(
    const bf16* __restrict__ A, const bf16* __restrict__ B,
    const float* __restrict__ bout, float* __restrict__ out) {
  __shared__ char As[8192];
  __shared__ char Bs[8192];
  const int tid = threadIdx.x;
  const int lane = tid & 63;
  const int wid = tid >> 6;
  const int wm = wid >> 1;
  const int wn = wid & 1;
  const size_t Mbase = (size_t)blockIdx.y * 128;
  const int Nbase = blockIdx.x * 128;

  const f32x4 zacc = {0.f, 0.f, 0.f, 0.f};
  f32x4 acc[4][4];
#pragma unroll
  for (int i = 0; i < 4; ++i)
#pragma unroll
    for (int j = 0; j < 4; ++j) acc[i][j] = zacc;

  for (int kc = 0; kc < 32; ++kc) {
    const int kb = kc * 32;
#pragma unroll
    for (int e = 0; e < 2; ++e) {
      const int id = e * 256 + tid;
      const int r = id >> 2;
      const int c8 = (id & 3) * 8;
      const int dst = ((r >> 4) * 64 + (c8 >> 3) * 16 + (r & 15)) * 16;
      const size_t m = Mbase + r;
      const bf16* arow = A + (m >> 6) * SLOT_E + (size_t)(m & 63) * NH;  // slot-aware row
      *(uint4*)(As + dst) = *(const uint4*)(arow + kb + c8);
      *(uint4*)(Bs + dst) = *(const uint4*)(B + (size_t)(Nbase + r) * NH + kb + c8);
    }
    __syncthreads();
    bf16x8 af[4], bfr[4];
#pragma unroll
    for (int i = 0; i < 4; ++i) {
      af[i]  = *(const bf16x8*)(As + ((wm * 4 + i) * 64 + lane) * 16);
      bfr[i] = *(const bf16x8*)(Bs + ((wn * 4 + i) * 64 + lane) * 16);
    }
#pragma unroll
    for (int i = 0; i < 4; ++i)
#pragma unroll
      for (int j = 0; j < 4; ++j)
        acc[i][j] = __builtin_amdgcn_mfma_f32_16x16x32_bf16(af[i], bfr[j], acc[i][j], 0, 0, 0);
    __syncthreads();
  }
  const int qq = lane >> 4, ml = lane & 15;
#pragma unroll
  for (int i = 0; i < 4; ++i)
#pragma unroll
    for (int j = 0; j < 4; ++j)
#pragma unroll
      for (int r = 0; r < 4; ++r) {
        const size_t m = Mbase + wm * 64 + i * 16 + qq * 4 + r;
        const int n = Nbase + wn * 64 + j * 16 + ml;
        out[m * NO + n] = acc[i][j][r] + bout[n];
      }
}

// ---------------- host ----------------
extern "C" void kernel_launch(void* const* d_in, const int* in_sizes, int n_in,
                              void* d_out, int out_size, void* d_ws, size_t ws_size,
                              hipStream_t stream) {
  (void)in_sizes; (void)n_in; (void)out_size; (void)ws_size;
  const float* x    = (const float*)d_in[0];
  const float* Wih0 = (const float*)d_in[1];
  const float* Whh0 = (const float*)d_in[2];
  const float* bih0 = (const float*)d_in[3];
  const float* bhh0 = (const float*)d_in[4];
  const float* Wih1 = (const float*)d_in[5];
  const float* Whh1 = (const float*)d_in[6];
  const float* bih1 = (const float*)d_in[7];
  const float* bhh1 = (const float*)d_in[8];
  const float* Wout = (const float*)d_in[9];
  const float* bout = (const float*)d_in[10];
  float* out = (float*)d_out;
  char* ws = (char*)d_ws;

  bf16*  xbf    = (bf16*)(ws + OFF_XBF);
  bf16*  wsw0   = (bf16*)(ws + OFF_WSW0);
  bf16*  wsw1   = (bf16*)(ws + OFF_WSW1);
  bf16*  woutbf = (bf16*)(ws + OFF_WOUT);
  float* bias0  = (float*)(ws + OFF_B0);
  float* bias1  = (float*)(ws + OFF_B1);
  bf16*  h1hist = (bf16*)(ws + OFF_H1);
  bf16*  h2hist = (bf16*)(ws + OFF_H2);
  int*   flags  = (int*)(ws + OFF_FLAGS);

  k_convert_x<<<8192, 256, 0, stream>>>(x, xbf);
  k_build_wsw<<<14336, 256, 0, stream>>>(Wih0, Whh0, Wih1, Whh1, wsw0, wsw1);
  k_small<<<2048, 256, 0, stream>>>(Wout, bih0, bhh0, bih1, bhh1, woutbf, bias0, bias1, flags);
  lstm_recur<<<256, 256, 0, stream>>>(xbf, wsw0, wsw1, bias0, bias1, h1hist, h2hist, flags);
  gemm_out<<<dim3(4, 256), 256, 0, stream>>>(h2hist, woutbf, bout, out);
}

// Round 4
// 6960.701 us; speedup vs baseline: 3.7354x; 1.2450x over previous
//
#include <hip/hip_runtime.h>
#include <hip/hip_bf16.h>
#include <cstdint>
#include <cstddef>

typedef short bf16x8 __attribute__((ext_vector_type(8)));
typedef float f32x4  __attribute__((ext_vector_type(4)));
typedef __hip_bfloat16 bf16;
typedef unsigned long long u64;

#define NT_T 512
#define NB   64
#define NI   512
#define NH   1024
#define NO   512

// h history slots: 64x1024 bf16 + 128-element pad (no cache line straddles slots;
// write-once addresses => plain cached loads are coherent by construction)
static constexpr size_t SLOT_E = (size_t)NB * NH + 128;
static constexpr size_t SLOT_B = SLOT_E * 2;

// ---------------- workspace layout (bytes, all 256-aligned) ----------------
static constexpr size_t OFF_XBF   = 0;
static constexpr size_t SZ_XBF    = (size_t)NT_T * NB * NI * 2;
static constexpr size_t OFF_WSW0  = OFF_XBF + SZ_XBF;
static constexpr size_t SZ_WSW0   = 128ull * 98304;
static constexpr size_t OFF_WSW1  = OFF_WSW0 + SZ_WSW0;
static constexpr size_t SZ_WSW1   = 128ull * 131072;
static constexpr size_t OFF_WOUT  = OFF_WSW1 + SZ_WSW1;
static constexpr size_t SZ_WOUT   = (size_t)NO * NH * 2;
static constexpr size_t OFF_B0    = OFF_WOUT + SZ_WOUT;
static constexpr size_t OFF_B1    = OFF_B0 + 4096 * 4;
static constexpr size_t OFF_H1    = OFF_B1 + 4096 * 4;
static constexpr size_t SZ_H1     = (size_t)NT_T * SLOT_B;
static constexpr size_t OFF_H2    = OFF_H1 + SZ_H1;
static constexpr size_t SZ_H2     = (size_t)NT_T * SLOT_B;
static constexpr size_t OFF_CNT   = OFF_H2 + SZ_H2;    // c1[512] then c2[512] ints
// total ~198.5 MB

__device__ __forceinline__ float sigm(float x) {
  return 1.0f / (1.0f + __expf(-x));
}
__device__ __forceinline__ float tanh_fast(float x) {
  x = fminf(15.0f, fmaxf(-15.0f, x));
  const float e = __expf(2.0f * x);
  return (e - 1.0f) / (e + 1.0f);
}

// wave-local wait: all 64 lanes poll the same word (coalesced broadcast load).
// Fast path: single probe. Compiler-only fence stops h-loads hoisting above the
// observed counter; HW-wise the subsequent miss is served from the coherence point.
__device__ __forceinline__ void wait_ge(const int* c, int tgt) {
  while (__hip_atomic_load(c, __ATOMIC_RELAXED, __HIP_MEMORY_SCOPE_AGENT) < tgt) {}
  asm volatile("" ::: "memory");
}

// ---------------- prep kernels ----------------
__global__ void k_convert_x(const float* __restrict__ x, bf16* __restrict__ xbf) {
  const size_t n = (size_t)NT_T * NB * NI;
  for (size_t i = (size_t)blockIdx.x * blockDim.x + threadIdx.x; i < n;
       i += (size_t)gridDim.x * blockDim.x)
    xbf[i] = __float2bfloat16(x[i]);
}

// Per-block, per-lane fragment-ordered weight images (see R1 notes).
// B-fragment of mfma_f32_16x16x32_bf16: lane l holds B[n = l&15][k = (l>>4)*8 + j].
// Layout: [blk][nt(2)][ks][lane(64)][j(8)]; K-concat: L0 [W_ih0|W_hh0] ks 0..47,
// L1 [W_ih1|W_hh1] ks 0..63. Gate rows per block: [i f g o] x 8 cols at blk*8.
__global__ void k_build_wsw(const float* __restrict__ Wih0, const float* __restrict__ Whh0,
                            const float* __restrict__ Wih1, const float* __restrict__ Whh1,
                            bf16* __restrict__ wsw0, bf16* __restrict__ wsw1) {
  const size_t L0N = 128ull * 2 * 48 * 64 * 8;
  const size_t L1N = 128ull * 2 * 64 * 64 * 8;
  const size_t n = L0N + L1N;
  for (size_t i = (size_t)blockIdx.x * blockDim.x + threadIdx.x; i < n;
       i += (size_t)gridDim.x * blockDim.x) {
    if (i < L0N) {
      size_t idx = i;
      const int j = idx & 7;    idx >>= 3;
      const int lane = idx & 63; idx >>= 6;
      const int ks = (int)(idx % 48); idx /= 48;
      const int nt = idx & 1;
      const int blk = (int)(idx >> 1);
      const int nl = nt * 16 + (lane & 15);
      const int k = ks * 32 + (lane >> 4) * 8 + j;
      const int grow = (nl >> 3) * 1024 + blk * 8 + (nl & 7);
      const float v = (k < 512) ? Wih0[(size_t)grow * 512 + k]
                                : Whh0[(size_t)grow * 1024 + (k - 512)];
      wsw0[i] = __float2bfloat16(v);
    } else {
      size_t idx = i - L0N;
      const size_t o = idx;
      const int j = idx & 7;    idx >>= 3;
      const int lane = idx & 63; idx >>= 6;
      const int ks = (int)(idx % 64); idx /= 64;
      const int nt = idx & 1;
      const int blk = (int)(idx >> 1);
      const int nl = nt * 16 + (lane & 15);
      const int k = ks * 32 + (lane >> 4) * 8 + j;
      const int grow = (nl >> 3) * 1024 + blk * 8 + (nl & 7);
      const float v = (k < 1024) ? Wih1[(size_t)grow * 1024 + k]
                                 : Whh1[(size_t)grow * 1024 + (k - 1024)];
      wsw1[o] = __float2bfloat16(v);
    }
  }
}

__global__ void k_small(const float* __restrict__ Wout,
                        const float* __restrict__ bih0, const float* __restrict__ bhh0,
                        const float* __restrict__ bih1, const float* __restrict__ bhh1,
                        bf16* __restrict__ woutbf, float* __restrict__ bias0,
                        float* __restrict__ bias1, int* __restrict__ cnt) {
  const int i = blockIdx.x * 256 + threadIdx.x;
  if (i < NO * NH) woutbf[i] = __float2bfloat16(Wout[i]);
  if (i < 4096) {
    bias0[i] = bih0[i] + bhh0[i];
    bias1[i] = bih1[i] + bhh1[i];
  }
  if (i < 1024) cnt[i] = 0;
}

// ---------------- persistent fused 2-layer LSTM recurrence ----------------
// grid = 256 x 256, 1 block/CU. blocks 0..127: layer0, 128..255: layer1.
// NO global barrier: per-layer per-timestep arrival counters (target 128).
// Layers fully decoupled (h1 is write-once history => L0 never waits on L1 and
// runs ahead; L1's c1[t] waits are then pre-satisfied single probes).
// Per-WAVE waits: L1 kh=1 waits only c2[t-1] and loads h2prev while kh=0 waits c1[t].
// L0 computes its x-contribution BEFORE waiting (x off-chain).
__global__ __launch_bounds__(256) void lstm_recur(
    const bf16* __restrict__ xbf, const bf16* __restrict__ wsw0, const bf16* __restrict__ wsw1,
    const float* __restrict__ bias0, const float* __restrict__ bias1,
    bf16* __restrict__ h1hist, bf16* __restrict__ h2hist, int* __restrict__ cnt) {
  __shared__ char Wlds[131072];
  __shared__ float red[64][33];

  const int tid = threadIdx.x;
  const int bid = blockIdx.x;
  const int layer = bid >> 7;
  const int blk = bid & 127;
  const int lane = tid & 63;
  const int wid = tid >> 6;
  const int mh = wid & 1;
  const int kh = wid >> 1;
  const int q = lane >> 4;
  const int ml = lane & 15;
  const int colbase = blk * 8;

  int* __restrict__ cme    = cnt + (layer ? 512 : 0);   // my layer's counters
  int* __restrict__ cother = cnt;                       // c1 (used by layer1 kh=0)

  { // weight slice -> LDS once
    const char* src = layer ? (const char*)wsw1 + (size_t)blk * 131072
                            : (const char*)wsw0 + (size_t)blk * 98304;
    const int nb = layer ? 131072 : 98304;
    for (int off = tid * 16; off < nb; off += 256 * 16)
      *(uint4*)(Wlds + off) = *(const uint4*)(src + off);
  }

  float biasv[2];
  {
    const float* bs = layer ? bias1 : bias0;
#pragma unroll
    for (int nt = 0; nt < 2; ++nt) {
      const int nl = nt * 16 + ml;
      biasv[nt] = bs[(nl >> 3) * 1024 + colbase + (nl & 7)];
    }
  }
  __syncthreads();

  const int KS = layer ? 64 : 48;

  float cstate[2] = {0.f, 0.f};
  const f32x4 zacc = {0.f, 0.f, 0.f, 0.f};

  for (int t = 0; t < NT_T; ++t) {
    const bf16* h1prev = h1hist + (size_t)(t - 1) * SLOT_E;  // valid iff t>0
    const bf16* h1cur  = h1hist + (size_t)t * SLOT_E;
    const bf16* h2prev = h2hist + (size_t)(t - 1) * SLOT_E;  // valid iff t>0

    f32x4 acc[2][2];
#pragma unroll
    for (int a1 = 0; a1 < 2; ++a1)
#pragma unroll
      for (int a2 = 0; a2 < 2; ++a2) acc[a1][a2] = zacc;

    // K-region: ks in [s,e), A rows from src (row stride rs), k offset koff.
    auto mm = [&](const bf16* src, int rs, int s, int e, int koff) {
#pragma unroll 8
      for (int ks = s; ks < e; ++ks) {
        const int kl = ks * 32 + q * 8 - koff;
        bf16x8 a[2];
#pragma unroll
        for (int mt = 0; mt < 2; ++mt)
          a[mt] = *(const bf16x8*)(src + (size_t)(mh * 32 + mt * 16 + ml) * rs + kl);
#pragma unroll
        for (int nt = 0; nt < 2; ++nt) {
          const bf16x8 b = *(const bf16x8*)(Wlds + ((size_t)(nt * KS + ks) * 64 + lane) * 16);
          acc[0][nt] = __builtin_amdgcn_mfma_f32_16x16x32_bf16(a[0], b, acc[0][nt], 0, 0, 0);
          acc[1][nt] = __builtin_amdgcn_mfma_f32_16x16x32_bf16(a[1], b, acc[1][nt], 0, 0, 0);
        }
      }
    };

    if (layer == 0) {
      // x-part first (no dependency on other blocks): 8 ks per wave
      mm(xbf + (size_t)t * NB * NI, NI, kh * 8, kh * 8 + 8, 0);
      if (t > 0) {
        wait_ge(&cme[t - 1], 128);                       // h1[t-1] complete
        mm(h1prev, NH, 16 + kh * 16, 32 + kh * 16, 512); // 16 h-ks per wave
      }
    } else {
      if (kh == 0) {
        wait_ge(&cother[t], 128);                        // h1[t] complete (usually pre-satisfied)
        mm(h1cur, NH, 0, 32, 0);
      } else if (t > 0) {
        wait_ge(&cme[t - 1], 128);                       // h2[t-1] complete (own-layer pace)
        mm(h2prev, NH, 32, 64, 1024);
      }
    }

    // cross-kh reduction: kh==1 publishes partials, kh==0 combines + bias
    if (kh == 1) {
#pragma unroll
      for (int mt = 0; mt < 2; ++mt)
#pragma unroll
        for (int nt = 0; nt < 2; ++nt)
#pragma unroll
          for (int r = 0; r < 4; ++r)
            red[mh * 32 + mt * 16 + q * 4 + r][nt * 16 + ml] = acc[mt][nt][r];
    }
    __syncthreads();
    if (kh == 0) {
#pragma unroll
      for (int mt = 0; mt < 2; ++mt)
#pragma unroll
        for (int nt = 0; nt < 2; ++nt)
#pragma unroll
          for (int r = 0; r < 4; ++r) {
            const int mloc = mh * 32 + mt * 16 + q * 4 + r;
            const int nloc = nt * 16 + ml;
            red[mloc][nloc] = acc[mt][nt][r] + red[mloc][nloc] + biasv[nt];
          }
    }
    __syncthreads();

    // elementwise LSTM cell: thread owns (b = tid>>2, cc0 = (tid&3)*2, +1) -> packed 4B sc1 store
    {
      const int b = tid >> 2;
      const int cc0 = (tid & 3) * 2;
      unsigned short hb[2];
#pragma unroll
      for (int e2 = 0; e2 < 2; ++e2) {
        const int cc = cc0 + e2;
        const float gi = red[b][cc];
        const float gf = red[b][8 + cc];
        const float gg = red[b][16 + cc];
        const float go = red[b][24 + cc];
        const float cn = sigm(gf) * cstate[e2] + sigm(gi) * tanh_fast(gg);
        cstate[e2] = cn;
        const float hv = sigm(go) * tanh_fast(cn);
        hb[e2] = __builtin_bit_cast(unsigned short, __float2bfloat16(hv));
      }
      const unsigned int packed = (unsigned int)hb[0] | ((unsigned int)hb[1] << 16);
      bf16* dstbase = (layer ? h2hist : h1hist) + (size_t)t * SLOT_E + (size_t)b * NH;
      __hip_atomic_store((unsigned int*)(dstbase + colbase + cc0), packed,
                         __ATOMIC_RELAXED, __HIP_MEMORY_SCOPE_AGENT);
    }

    // arrival: all waves' sc1 stores acked at coherence point (vmcnt(0) at barrier),
    // then one device-scope add to this layer's counter for step t
    __syncthreads();
    if (tid == 0)
      __hip_atomic_fetch_add(&cme[t], 1, __ATOMIC_RELAXED, __HIP_MEMORY_SCOPE_AGENT);
  }
}

// ---------------- output projection: h2hist(slots) @ W_out^T + b_out ----------------
__global__ __launch_bounds__(256) void gemm_out(
    const bf16* __restrict__ A, const bf16* __restrict__ B,
    const float* __restrict__ bout, float* __restrict__ out) {
  __shared__ char As[8192];
  __shared__ char Bs[8192];
  const int tid = threadIdx.x;
  const int lane = tid & 63;
  const int wid = tid >> 6;
  const int wm = wid >> 1;
  const int wn = wid & 1;
  const size_t Mbase = (size_t)blockIdx.y * 128;
  const int Nbase = blockIdx.x * 128;

  const f32x4 zacc = {0.f, 0.f, 0.f, 0.f};
  f32x4 acc[4][4];
#pragma unroll
  for (int i = 0; i < 4; ++i)
#pragma unroll
    for (int j = 0; j < 4; ++j) acc[i][j] = zacc;

  for (int kc = 0; kc < 32; ++kc) {
    const int kb = kc * 32;
#pragma unroll
    for (int e = 0; e < 2; ++e) {
      const int id = e * 256 + tid;
      const int r = id >> 2;
      const int c8 = (id & 3) * 8;
      const int dst = ((r >> 4) * 64 + (c8 >> 3) * 16 + (r & 15)) * 16;
      const size_t m = Mbase + r;
      const bf16* arow = A + (m >> 6) * SLOT_E + (size_t)(m & 63) * NH;  // slot-aware row
      *(uint4*)(As + dst) = *(const uint4*)(arow + kb + c8);
      *(uint4*)(Bs + dst) = *(const uint4*)(B + (size_t)(Nbase + r) * NH + kb + c8);
    }
    __syncthreads();
    bf16x8 af[4], bfr[4];
#pragma unroll
    for (int i = 0; i < 4; ++i) {
      af[i]  = *(const bf16x8*)(As + ((wm * 4 + i) * 64 + lane) * 16);
      bfr[i] = *(const bf16x8*)(Bs + ((wn * 4 + i) * 64 + lane) * 16);
    }
#pragma unroll
    for (int i = 0; i < 4; ++i)
#pragma unroll
      for (int j = 0; j < 4; ++j)
        acc[i][j] = __builtin_amdgcn_mfma_f32_16x16x32_bf16(af[i], bfr[j], acc[i][j], 0, 0, 0);
    __syncthreads();
  }
  const int qq = lane >> 4, ml = lane & 15;
#pragma unroll
  for (int i = 0; i < 4; ++i)
#pragma unroll
    for (int j = 0; j < 4; ++j)
#pragma unroll
      for (int r = 0; r < 4; ++r) {
        const size_t m = Mbase + wm * 64 + i * 16 + qq * 4 + r;
        const int n = Nbase + wn * 64 + j * 16 + ml;
        out[m * NO + n] = acc[i][j][r] + bout[n];
      }
}

// ---------------- host ----------------
extern "C" void kernel_launch(void* const* d_in, const int* in_sizes, int n_in,
                              void* d_out, int out_size, void* d_ws, size_t ws_size,
                              hipStream_t stream) {
  (void)in_sizes; (void)n_in; (void)out_size; (void)ws_size;
  const float* x    = (const float*)d_in[0];
  const float* Wih0 = (const float*)d_in[1];
  const float* Whh0 = (const float*)d_in[2];
  const float* bih0 = (const float*)d_in[3];
  const float* bhh0 = (const float*)d_in[4];
  const float* Wih1 = (const float*)d_in[5];
  const float* Whh1 = (const float*)d_in[6];
  const float* bih1 = (const float*)d_in[7];
  const float* bhh1 = (const float*)d_in[8];
  const float* Wout = (const float*)d_in[9];
  const float* bout = (const float*)d_in[10];
  float* out = (float*)d_out;
  char* ws = (char*)d_ws;

  bf16*  xbf    = (bf16*)(ws + OFF_XBF);
  bf16*  wsw0   = (bf16*)(ws + OFF_WSW0);
  bf16*  wsw1   = (bf16*)(ws + OFF_WSW1);
  bf16*  woutbf = (bf16*)(ws + OFF_WOUT);
  float* bias0  = (float*)(ws + OFF_B0);
  float* bias1  = (float*)(ws + OFF_B1);
  bf16*  h1hist = (bf16*)(ws + OFF_H1);
  bf16*  h2hist = (bf16*)(ws + OFF_H2);
  int*   cnt    = (int*)(ws + OFF_CNT);

  k_convert_x<<<8192, 256, 0, stream>>>(x, xbf);
  k_build_wsw<<<14336, 256, 0, stream>>>(Wih0, Whh0, Wih1, Whh1, wsw0, wsw1);
  k_small<<<2048, 256, 0, stream>>>(Wout, bih0, bhh0, bih1, bhh1, woutbf, bias0, bias1, cnt);
  lstm_recur<<<256, 256, 0, stream>>>(xbf, wsw0, wsw1, bias0, bias1, h1hist, h2hist, cnt);
  gemm_out<<<dim3(4, 256), 256, 0, stream>>>(h2hist, woutbf, bout, out);
}